// Round 7
// baseline (366.673 us; speedup 1.0000x reference)
//
#include <hip/hip_runtime.h>

// RandomEqualize: PIL-style histogram equalization per (batch, channel).
// Input: float32 (64,3,512,512), exact integer values in [0,255].
// N = 192 channels, P = 262144 pixels/channel.
//
// 2-kernel pipeline, no intermediate buffer:
//  K1: pure 32-copy bank-strided LDS histogram (32 KB, ds_add conflict-free),
//      BPC_H=4, REGULAR cached loads -> input ends L3-resident (201 MB < 256
//      MB L3; proven to survive a kernel boundary by the R3 fused kernel's
//      FETCH=198MB over a double read). Floor ~31 us.
//  K2: reduce partials -> PIL LUT -> 16-replica LDS LUT gather applied to the
//      L3-resident float input; coalesced NT float4 stores (never evict the
//      input). BPC_A=16 + launch_bounds(256,8) -> 8 blocks/CU = 32 waves/CU
//      (R6's occupancy win). Floor ~35 us (201 MB NT write + L3 reads).
// The u8 pack intermediate (R2-R6) is dropped: it saved only L3-hit reads
// while costing 50 MB of real stores + writebacks on K1's critical path.

#define NBINS 256
#define BPC_H 4                   // hist blocks per channel  (768 blocks)
#define BPC_A 16                  // apply blocks per channel (3072 blocks)
#define NVEC_H 16384              // float4 packets per hist block (P/BPC_H/4)
#define NVEC_A 4096               // float4 packets per apply block (P/BPC_A/4)
#define NCOPY_A 16                // LUT replicas

typedef float vfloat4 __attribute__((ext_vector_type(4)));

// ---------------- K1: histogram ----------------
__global__ __launch_bounds__(256) void eq_hist_kernel(
    const float* __restrict__ in, unsigned int* __restrict__ phist) {
    __shared__ unsigned int lh[NBINS * 32];  // 32 KB, word (bin*32+copy) -> bank=copy
    const int t = threadIdx.x;
    const int copy = t & 31;

    for (int i = t; i < NBINS * 32; i += 256) lh[i] = 0u;
    __syncthreads();

    const size_t basev = (size_t)blockIdx.x * NVEC_H;   // float4 units
    const float4* vin = (const float4*)in + basev;

    #pragma unroll 4
    for (int i = t; i < NVEC_H; i += 256) {
        float4 v = vin[i];                    // cached: input stays L3-resident
        int ix = min(max((int)v.x, 0), 255);
        int iy = min(max((int)v.y, 0), 255);
        int iz = min(max((int)v.z, 0), 255);
        int iw = min(max((int)v.w, 0), 255);
        atomicAdd(&lh[ix * 32 + copy], 1u);   // bank = copy = lane&31: conflict-free
        atomicAdd(&lh[iy * 32 + copy], 1u);
        atomicAdd(&lh[iz * 32 + copy], 1u);
        atomicAdd(&lh[iw * 32 + copy], 1u);
    }
    __syncthreads();

    // thread t owns bin t; staggered copy index keeps lanes on distinct banks
    unsigned int hsum = 0;
    #pragma unroll
    for (int c = 0; c < 32; ++c) hsum += lh[t * 32 + ((t + c) & 31)];
    phist[(size_t)blockIdx.x * NBINS + t] = hsum;   // partial, no atomics
}

// ---------------- K2: LUT build + apply ----------------
__global__ __launch_bounds__(256, 8) void eq_lut_apply_kernel(
    const float* __restrict__ in, const unsigned int* __restrict__ phist,
    float* __restrict__ out, int P) {
    __shared__ float slut[NBINS * NCOPY_A];   // 16 KB, 16x bank-replicated LUT
    __shared__ unsigned int s[NBINS];
    __shared__ int sidx[NBINS];
    const int t = threadIdx.x;
    const int copy = t & (NCOPY_A - 1);
    const int chan = blockIdx.x >> 4;         // BPC_A = 16

    // per-channel hist from BPC_H partials
    unsigned int h = 0;
    const unsigned int* pb = phist + (size_t)chan * BPC_H * NBINS;
    #pragma unroll
    for (int b = 0; b < BPC_H; ++b) h += pb[b * NBINS + t];
    s[t] = h;
    sidx[t] = (h != 0u) ? t : -1;
    __syncthreads();

    // max-reduce: last nonzero bin index
    for (int off = 128; off > 0; off >>= 1) {
        if (t < off) sidx[t] = max(sidx[t], sidx[t + off]);
        __syncthreads();
    }
    const int last_idx = sidx[0];
    const int last_val = (int)s[last_idx];
    const int step = (P - last_val) / 255;

    // Hillis-Steele inclusive scan
    for (int off = 1; off < NBINS; off <<= 1) {
        unsigned int v = (t >= off) ? s[t - off] : 0u;
        __syncthreads();
        s[t] += v;
        __syncthreads();
    }

    float lv;
    if (step == 0) {
        lv = (float)t;   // pass-through: identity LUT
    } else {
        int csp = (t == 0) ? 0 : (int)s[t - 1];
        lv = (float)min(max((csp + (step >> 1)) / step, 0), 255);
    }
    #pragma unroll
    for (int c = 0; c < NCOPY_A; ++c)
        slut[t * NCOPY_A + ((t + c) & (NCOPY_A - 1))] = lv;  // 2-way: free
    __syncthreads();

    // apply: L3-resident float reads, 16-replica LUT gather, coalesced NT stores
    const size_t basev = (size_t)blockIdx.x * NVEC_A;   // float4 units
    const float4* vin = (const float4*)in + basev;
    vfloat4* vout = (vfloat4*)out + basev;

    #pragma unroll 4
    for (int i = t; i < NVEC_A; i += 256) {
        float4 v = vin[i];
        vfloat4 r;
        r.x = slut[min(max((int)v.x, 0), 255) * NCOPY_A + copy];
        r.y = slut[min(max((int)v.y, 0), 255) * NCOPY_A + copy];
        r.z = slut[min(max((int)v.z, 0), 255) * NCOPY_A + copy];
        r.w = slut[min(max((int)v.w, 0), 255) * NCOPY_A + copy];
        __builtin_nontemporal_store(r, &vout[i]);   // lane-consecutive: coalesced
    }
}

extern "C" void kernel_launch(void* const* d_in, const int* in_sizes, int n_in,
                              void* d_out, int out_size, void* d_ws, size_t ws_size,
                              hipStream_t stream) {
    const float* img = (const float*)d_in[0];
    float* out = (float*)d_out;

    const int P = 512 * 512;        // pixels per channel
    const int total = in_sizes[0];  // 64*3*512*512 elements
    const int N = total / P;        // 192 channels

    unsigned int* phist = (unsigned int*)d_ws;   // N*BPC_H*256 u32 = 768 KB

    eq_hist_kernel<<<N * BPC_H, 256, 0, stream>>>(img, phist);
    eq_lut_apply_kernel<<<N * BPC_A, 256, 0, stream>>>(img, phist, out, P);
}

// Round 9
// 344.343 us; speedup vs baseline: 1.0649x; 1.0649x over previous
//
#include <hip/hip_runtime.h>

// RandomEqualize: PIL-style histogram equalization per (batch, channel).
// Input: float32 (64,3,512,512), exact integer values in [0,255].
// N = 192 channels, P = 262144 pixels/channel.
//
// 2-kernel pipeline (R6 structure; K2 stores switched NT -> regular):
//  K1: 32-copy bank-strided LDS histogram (32 KB, ds_add conflict-free),
//      BPC_H=4, NT input loads (input is dead after K1; keep L3 for pack).
//      Packs clamped pixels to u8 (cached stores -> L3-resident, 50 MB).
//  K2: reduce partials -> PIL LUT -> 16-replica LDS LUT gather over the u8
//      pack stream (L3-hit); REGULAR cached float4 stores. NT stores were
//      ~4 TB/s effective (bypass L2/L3 write path) and made K2 ~53 us; with
//      cached stores the write set (197 MB) + pack (50 MB) still fits L3.
//      BPC_A=16 + launch_bounds(256,8) -> 8 blocks/CU (R6's occupancy win).

#define NBINS 256
#define BPC_H 4                   // hist blocks per channel  (768 blocks)
#define BPC_A 16                  // apply blocks per channel (3072 blocks)
#define NVEC_H 16384              // float4 packets per hist block (P/BPC_H/4)
#define NVEC_A 4096               // u32 packets per apply block  (P/BPC_A/4)
#define NCOPY_A 16                // LUT replicas

typedef float vfloat4 __attribute__((ext_vector_type(4)));

// ---------------- K1: histogram + u8 pack ----------------
__global__ __launch_bounds__(256) void eq_hist_pack_kernel(
    const float* __restrict__ in, unsigned int* __restrict__ pack,
    unsigned int* __restrict__ phist) {
    __shared__ unsigned int lh[NBINS * 32];  // 32 KB, word (bin*32+copy) -> bank=copy
    const int t = threadIdx.x;
    const int copy = t & 31;

    for (int i = t; i < NBINS * 32; i += 256) lh[i] = 0u;
    __syncthreads();

    const size_t basev = (size_t)blockIdx.x * NVEC_H;   // float4 / u32 units
    const vfloat4* vin = (const vfloat4*)in + basev;
    unsigned int* pout = pack + basev;                  // one u32 per 4 pixels

    #pragma unroll 4
    for (int i = t; i < NVEC_H; i += 256) {
        vfloat4 v = __builtin_nontemporal_load(&vin[i]);  // dead after K1
        int ix = min(max((int)v.x, 0), 255);
        int iy = min(max((int)v.y, 0), 255);
        int iz = min(max((int)v.z, 0), 255);
        int iw = min(max((int)v.w, 0), 255);
        atomicAdd(&lh[ix * 32 + copy], 1u);   // bank = copy = lane&31: conflict-free
        atomicAdd(&lh[iy * 32 + copy], 1u);
        atomicAdd(&lh[iz * 32 + copy], 1u);
        atomicAdd(&lh[iw * 32 + copy], 1u);
        pout[i] = (unsigned)ix | ((unsigned)iy << 8) |
                  ((unsigned)iz << 16) | ((unsigned)iw << 24);
    }
    __syncthreads();

    // thread t owns bin t; staggered copy index keeps lanes on distinct banks
    unsigned int hsum = 0;
    #pragma unroll
    for (int c = 0; c < 32; ++c) hsum += lh[t * 32 + ((t + c) & 31)];
    phist[(size_t)blockIdx.x * NBINS + t] = hsum;   // partial, no atomics
}

// ---------------- K2: LUT build + apply ----------------
__global__ __launch_bounds__(256, 8) void eq_lut_apply_kernel(
    const unsigned int* __restrict__ pack, const unsigned int* __restrict__ phist,
    float* __restrict__ out, int P) {
    __shared__ float slut[NBINS * NCOPY_A];   // 16 KB, 16x bank-replicated LUT
    __shared__ unsigned int s[NBINS];
    __shared__ int sidx[NBINS];
    const int t = threadIdx.x;
    const int copy = t & (NCOPY_A - 1);
    const int chan = blockIdx.x >> 4;         // BPC_A = 16

    // per-channel hist from BPC_H partials
    unsigned int h = 0;
    const unsigned int* pb = phist + (size_t)chan * BPC_H * NBINS;
    #pragma unroll
    for (int b = 0; b < BPC_H; ++b) h += pb[b * NBINS + t];
    s[t] = h;
    sidx[t] = (h != 0u) ? t : -1;
    __syncthreads();

    // max-reduce: last nonzero bin index
    for (int off = 128; off > 0; off >>= 1) {
        if (t < off) sidx[t] = max(sidx[t], sidx[t + off]);
        __syncthreads();
    }
    const int last_idx = sidx[0];
    const int last_val = (int)s[last_idx];
    const int step = (P - last_val) / 255;

    // Hillis-Steele inclusive scan
    for (int off = 1; off < NBINS; off <<= 1) {
        unsigned int v = (t >= off) ? s[t - off] : 0u;
        __syncthreads();
        s[t] += v;
        __syncthreads();
    }

    float lv;
    if (step == 0) {
        lv = (float)t;   // pass-through: identity LUT
    } else {
        int csp = (t == 0) ? 0 : (int)s[t - 1];
        lv = (float)min(max((csp + (step >> 1)) / step, 0), 255);
    }
    #pragma unroll
    for (int c = 0; c < NCOPY_A; ++c)
        slut[t * NCOPY_A + ((t + c) & (NCOPY_A - 1))] = lv;  // 2-way: free
    __syncthreads();

    // apply: u32 packed pixels, 16-replica LUT gather, coalesced cached stores
    const size_t basev = (size_t)blockIdx.x * NVEC_A;   // u32 / float4 units
    const unsigned int* pin = pack + basev;             // u8 pixels, L3-resident
    float4* vout = (float4*)out + basev;

    #pragma unroll 4
    for (int i = t; i < NVEC_A; i += 256) {
        unsigned int p = pin[i];
        float4 r;
        r.x = slut[(p & 255u) * NCOPY_A + copy];
        r.y = slut[((p >> 8) & 255u) * NCOPY_A + copy];
        r.z = slut[((p >> 16) & 255u) * NCOPY_A + copy];
        r.w = slut[(p >> 24) * NCOPY_A + copy];
        vout[i] = r;   // regular store: absorbs into L2/L3 at fill-rate BW
    }
}

extern "C" void kernel_launch(void* const* d_in, const int* in_sizes, int n_in,
                              void* d_out, int out_size, void* d_ws, size_t ws_size,
                              hipStream_t stream) {
    const float* img = (const float*)d_in[0];
    float* out = (float*)d_out;

    const int P = 512 * 512;        // pixels per channel
    const int total = in_sizes[0];  // 64*3*512*512 elements
    const int N = total / P;        // 192 channels

    // ws layout: packed u8 pixels (total bytes) | partial hists (768 KB)
    unsigned int* pack  = (unsigned int*)d_ws;
    unsigned int* phist = (unsigned int*)((char*)d_ws + (size_t)total);

    eq_hist_pack_kernel<<<N * BPC_H, 256, 0, stream>>>(img, pack, phist);
    eq_lut_apply_kernel<<<N * BPC_A, 256, 0, stream>>>(pack, phist, out, P);
}